// Round 4
// baseline (1195.001 us; speedup 1.0000x reference)
//
#include <hip/hip_runtime.h>
#include <math.h>

// BWNet scan, R3 "dataflow": 16 scan blocks, ZERO barrier RMWs.
// Producers publish via sc1 stores + tagged words / release flags;
// consumers poll with parallel per-lane sc1 loads + ballot.
// Control state is wave-register-replicated (3 __syncthreads/step).
// Blocks 16..255 zero unit_logits rows [steps..8192) concurrently.

typedef float v4f __attribute__((ext_vector_type(4)));
typedef float v2f __attribute__((ext_vector_type(2)));
typedef unsigned long long u64;

#define N_ENT 8192
#define EMB   256
#define KD    32
#define ARD   1024
#define UT    233
#define NSCAN 16
#define NZBLK 240
#define NBLK  256
#define CPB   512   // key columns per scan block
#define ARB   64    // ar-slice length per scan block

// float-index offsets into d_ws
#define WS_KEYS  0        // 32*8192, k-major
#define WS_C0    262144   // 256: b_a0 + relu(W_fe@um + b_fe)
#define WS_I0P   262400   // 256*16 floats, [tid*16 + b]
#define WS_FLAGA 266496   // 64 ints (b*4+w)
#define WS_PK0   266624   // 64 u64 (sum | tag)
#define WS_PK1   266752   // 64 u64 (max | idx<<8 | tag)

struct Params {
  const float *um, *emask, *enc, *arin, *W_fe, *b_fe, *W_k, *b_k,
              *W_a0, *b_a0, *W_a1, *b_a1, *W_f, *b_f, *W_i0, *b_i0,
              *W_i1, *b_i1, *W_o, *b_o, *ln_g, *ln_b, *W_a3, *b_a3;
  const int* ct;
  float* out;
  float* wsf;
  int*   wsi;
};

__device__ __forceinline__ void st_af(float* p, float v) {
  __hip_atomic_store(p, v, __ATOMIC_RELAXED, __HIP_MEMORY_SCOPE_AGENT);
}
__device__ __forceinline__ int ali(int* p) {
  return __hip_atomic_load(p, __ATOMIC_RELAXED, __HIP_MEMORY_SCOPE_AGENT);
}
__device__ __forceinline__ u64 alu64(u64* p) {
  return __hip_atomic_load(p, __ATOMIC_RELAXED, __HIP_MEMORY_SCOPE_AGENT);
}
__device__ __forceinline__ u64 shfl_u64(u64 v, int src) {
  int lo = __shfl((int)(unsigned)(v & 0xffffffffu), src);
  int hi = __shfl((int)(unsigned)(v >> 32), src);
  return ((u64)(unsigned)hi << 32) | (u64)(unsigned)lo;
}
// LayerNorm over a 32-lane group (lanes l and l+32 duplicate).
__device__ __forceinline__ float ln32(float a, float g, float b) {
  float s = a;
  #pragma unroll
  for (int m = 1; m <= 16; m <<= 1) s += __shfl_xor(s, m);
  const float mean = s * (1.f / 32.f);
  const float d = a - mean;
  float vv = d * d;
  #pragma unroll
  for (int m = 1; m <= 16; m <<= 1) vv += __shfl_xor(vv, m);
  return d * rsqrtf(vv * (1.f / 32.f) + 1e-5f) * g + b;
}

// ---------------- init: keys GEMM (k-major), c0 ----------------
__global__ __launch_bounds__(256) void k_init(Params p) {
  __shared__ float enc_s[32 * 260];
  __shared__ float um_s[UT];
  const int tid = threadIdx.x, bid = blockIdx.x;
  float* keys = p.wsf + WS_KEYS;

  if (bid == 0 && tid < UT) um_s[tid] = p.um[tid];

  const int j0 = bid * 32;
  #pragma unroll
  for (int i = 0; i < 8; ++i) {
    int idx = i * 256 + tid;
    int row = idx >> 6, c4 = idx & 63;
    v4f v = *(const v4f*)(p.enc + (size_t)(j0 + row) * EMB + c4 * 4);
    *(v4f*)&enc_s[row * 260 + c4 * 4] = v;
  }
  __syncthreads();
  {
    const int jl = tid >> 3, kg = tid & 7;
    float acc[4];
    #pragma unroll
    for (int kk = 0; kk < 4; ++kk) acc[kk] = p.b_k[kg * 4 + kk];
    for (int e4 = 0; e4 < 64; ++e4) {
      v4f x = *(const v4f*)&enc_s[jl * 260 + e4 * 4];
      #pragma unroll
      for (int kk = 0; kk < 4; ++kk) {
        v4f w = *(const v4f*)(p.W_k + (size_t)(kg * 4 + kk) * EMB + e4 * 4);
        acc[kk] += x.x * w.x + x.y * w.y + x.z * w.z + x.w * w.w;
      }
    }
    const int j = j0 + jl;
    #pragma unroll
    for (int kk = 0; kk < 4; ++kk) keys[(size_t)(kg * 4 + kk) * N_ENT + j] = acc[kk];
  }
  if (bid == 0) {  // c0 = relu(W_fe@um + b_fe) + b_a0
    float a = p.b_fe[tid];
    const float* wr = p.W_fe + (size_t)tid * UT;
    for (int u = 0; u < UT; ++u) a += wr[u] * um_s[u];
    p.wsf[WS_C0 + tid] = fmaxf(a, 0.f) + p.b_a0[tid];
  }
}

// ---------------- main: scan (blocks 0..15) + zeroing (16..255) ----------------
__global__ __launch_bounds__(256, 1) void k_scan(Params p) {
  const int tid = threadIdx.x, bid = blockIdx.x;
  const int lane = tid & 63, wv = tid >> 6, l32 = lane & 31;
  int ctv = p.ct[0];
  const int steps = ctv < 0 ? 0 : (ctv > 64 ? 64 : ctv);
  const size_t NN = (size_t)N_ENT * N_ENT;

  if (bid >= NSCAN) {  // -------- zero role --------
    v4f z = (v4f){0.f, 0.f, 0.f, 0.f};
    v4f* o4 = (v4f*)p.out;
    const size_t tot = NN / 4;
    for (size_t i = (size_t)steps * (N_ENT / 4) + (size_t)(bid - NSCAN) * 256 + tid;
         i < tot; i += (size_t)NZBLK * 256)
      __builtin_nontemporal_store(z, o4 + i);
    return;
  }

  // -------- scan role --------
  __shared__ float kslice[KD * CPB];   // 64KB, [k][col]
  __shared__ float wa3s[ARB * 33];     // 8.4KB, bank-padded
  __shared__ float ri0_s[8 * 33];
  __shared__ float x_i1[32], q_s[32];
  __shared__ float garr[128], gb_s[128], b_a1s[32];
  __shared__ unsigned pb_lds[256];
  __shared__ float lds_pad[2048];      // push LDS > 80KB -> 1 block/CU

  float* keys = p.wsf + WS_KEYS;
  float* i0p  = p.wsf + WS_I0P;
  int*   flagA = p.wsi + WS_FLAGA;
  u64*   pk0 = (u64*)(p.wsf + WS_PK0);
  u64*   pk1 = (u64*)(p.wsf + WS_PK1);

  // ---- registers ----
  float ar_reg = p.arin[bid * ARB + lane];       // lane l holds ar[bid*64+l]
  float ba3_reg = p.b_a3[bid * ARB + lane];
  const float lngr = p.ln_g[l32], lnbr = p.ln_b[l32];
  float h_reg = 0.f, q_reg = 0.f;
  u64 pb0 = 0ull, pb1 = 0ull;                    // picked bits: entities [lane*128,+128)
  int active = 1, done = 0;
  const float c0r = p.wsf[WS_C0 + tid];

  float w0f[64];  // W_a0 row tid, cols [bid*64, +64)
  {
    const v4f* s = (const v4f*)(p.W_a0 + (size_t)tid * ARD + bid * ARB);
    #pragma unroll
    for (int i = 0; i < 16; ++i) {
      v4f v = s[i];
      w0f[4*i] = v.x; w0f[4*i+1] = v.y; w0f[4*i+2] = v.z; w0f[4*i+3] = v.w;
    }
  }
  // initial i0 partial publish (before heavy LDS staging: unblock others early)
  {
    float part = 0.f;
    #pragma unroll
    for (int i = 0; i < 64; ++i) part += w0f[i] * __shfl(ar_reg, i);
    st_af(&i0p[tid * 16 + bid], part);
    if (lane == 0)
      __hip_atomic_store(&flagA[bid * 4 + wv], 1, __ATOMIC_RELEASE, __HIP_MEMORY_SCOPE_AGENT);
  }

  v4f w1[8];    // W_a1 row tid>>3, col-group (tid&7)*32
  { const float* s = p.W_a1 + (size_t)(tid >> 3) * EMB + (tid & 7) * 32;
    #pragma unroll
    for (int i = 0; i < 8; ++i) w1[i] = ((const v4f*)s)[i]; }
  v4f wg[8];    // LSTM gate row tid>>1, half tid&1
  { const int rowg = tid >> 1, g = rowg >> 5, r = rowg & 31, half = tid & 1;
    const float* W = (g == 0) ? p.W_f : (g == 1) ? p.W_i0 : (g == 2) ? p.W_i1 : p.W_o;
    const float* s = W + r * 64 + half * 32;
    #pragma unroll
    for (int i = 0; i < 8; ++i) wg[i] = ((const v4f*)s)[i]; }

  // ---- LDS staging ----
  for (int i4 = tid; i4 < KD * (CPB / 4); i4 += 256) {
    int k = i4 >> 7, c4 = i4 & 127;
    v4f v = *(const v4f*)(keys + (size_t)k * N_ENT + (bid << 9) + c4 * 4);
    *(v4f*)&kslice[k * CPB + c4 * 4] = v;
  }
  for (int i4 = tid; i4 < ARB * 8; i4 += 256) {
    int r = i4 >> 3, c4 = i4 & 7;
    v4f v = *(const v4f*)(p.W_a3 + (size_t)(bid * ARB + r) * KD + c4 * 4);
    float* d = &wa3s[r * 33 + c4 * 4];
    d[0] = v.x; d[1] = v.y; d[2] = v.z; d[3] = v.w;
  }
  if (tid < 32) { b_a1s[tid] = p.b_a1[tid]; q_s[tid] = 0.f; }
  if (tid < 128) {
    const int g = tid >> 5, r = tid & 31;
    const float* bg = (g == 0) ? p.b_f : (g == 1) ? p.b_i0 : (g == 2) ? p.b_i1 : p.b_o;
    gb_s[tid] = bg[r];
  }
  if (tid == 0) lds_pad[0] = 0.f;
  __syncthreads();

  for (int t = 0; t < steps; ++t) {
    const int tagA = t + 1;
    // ==== wait for all i0 partials (per-lane flag poll, no RMW) ====
    {
      int guard = 0;
      while (true) {
        int f = ali(&flagA[lane]);
        if (__ballot(f == tagA) == ~0ull) break;
        __builtin_amdgcn_s_sleep(1);
        if (++guard > (1 << 20)) break;
      }
      (void)__hip_atomic_load(&flagA[lane], __ATOMIC_ACQUIRE, __HIP_MEMORY_SCOPE_AGENT);
    }
    // ==== gather i0 (plain vector loads, fresh after acquire-inv) ====
    {
      const v4f* ip = (const v4f*)(i0p + tid * 16);
      v4f g0 = ip[0], g1 = ip[1], g2 = ip[2], g3 = ip[3];
      float acc = c0r + g0.x + g0.y + g0.z + g0.w + g1.x + g1.y + g1.z + g1.w
                      + g2.x + g2.y + g2.z + g2.w + g3.x + g3.y + g3.z + g3.w;
      ri0_s[(tid >> 5) * 33 + (tid & 31)] = fmaxf(acc, 0.f);
    }
    __syncthreads();  // S1
    {  // i1 = relu(W_a1 @ ri0 + b_a1)
      const int r = tid >> 3, s8 = tid & 7;
      float p1 = 0.f;
      #pragma unroll
      for (int i = 0; i < 8; ++i) {
        const float* xx = &ri0_s[s8 * 33 + 4 * i];
        p1 += w1[i].x * xx[0] + w1[i].y * xx[1] + w1[i].z * xx[2] + w1[i].w * xx[3];
      }
      #pragma unroll
      for (int m = 4; m; m >>= 1) p1 += __shfl_xor(p1, m);
      if (s8 == 0) x_i1[r] = fmaxf(p1 + b_a1s[r], 0.f);
    }
    __syncthreads();  // S2
    {  // 4 LSTM gate matvecs -> garr (pre-activation applied)
      const int rowg = tid >> 1, g = rowg >> 5, half = tid & 1;
      const float* xsrc = half ? q_s : x_i1;
      float pg = 0.f;
      #pragma unroll
      for (int i = 0; i < 8; ++i)
        pg += wg[i].x * xsrc[4 * i] + wg[i].y * xsrc[4 * i + 1] +
              wg[i].z * xsrc[4 * i + 2] + wg[i].w * xsrc[4 * i + 3];
      pg += __shfl_xor(pg, 1);
      if (!half) {
        pg += gb_s[rowg];
        garr[rowg] = (g == 2) ? tanhf(pg) : 1.f / (1.f + __expf(-pg));
      }
    }
    __syncthreads();  // S3
    // ==== per-wave (redundant): 3 LNs, qn, state gate ====
    float qn;
    {
      const float af = garr[l32];
      const float am = garr[32 + l32] * garr[64 + l32];
      const float ao = garr[96 + l32];
      const float f = ln32(af, lngr, lnbr);
      const float rm = ln32(am, lngr, lnbr);
      const float o = ln32(ao, lngr, lnbr);
      const float nh = rm + f * h_reg;
      const float qv = tanhf(nh) * o;
      qn = qv;
      if (active) { h_reg = nh; q_reg = qv; }
      if (tid < 32) q_s[tid] = q_reg;  // consumed after next step's S2
    }
    // ==== sweep own 2 cols; per-wave reduce; publish tagged payload ====
    float v0, v1;
    {
      float d0 = 0.f, d1 = 0.f;
      #pragma unroll
      for (int k = 0; k < 32; ++k) {
        const float qk = __shfl(qn, k);
        const v2f kk = *(const v2f*)&kslice[k * CPB + 2 * tid];
        d0 += qk * kk.x; d1 += qk * kk.y;
      }
      const float s0 = 1.f / (1.f + __expf(-d0));
      const float s1 = 1.f / (1.f + __expf(-d1));
      v0 = __expf(__logf(s0) * 1.25f);
      v1 = __expf(__logf(s1) * 1.25f);
      float sv = v0 + v1;
      float mv; int mi;
      const int gi0 = (bid << 9) + 2 * tid;
      if (v1 > v0) { mv = v1; mi = gi0 + 1; } else { mv = v0; mi = gi0; }
      #pragma unroll
      for (int m = 1; m <= 32; m <<= 1) {
        sv += __shfl_xor(sv, m);
        const float om = __shfl_xor(mv, m);
        const int oi = __shfl_xor(mi, m);
        if (om > mv || (om == mv && oi < mi)) { mv = om; mi = oi; }
      }
      if (lane == 0) {
        const u64 tg = (u64)(unsigned)(t + 1);
        u64 P0 = ((u64)__float_as_uint(sv) << 32) | tg;
        u64 P1 = ((u64)__float_as_uint(mv) << 32) | ((u64)(unsigned)mi << 8) | tg;
        const int s = bid * 4 + wv;
        __hip_atomic_store(&pk0[s], P0, __ATOMIC_RELAXED, __HIP_MEMORY_SCOPE_AGENT);
        __hip_atomic_store(&pk1[s], P1, __ATOMIC_RELAXED, __HIP_MEMORY_SCOPE_AGENT);
      }
    }
    // ==== poll all 64 wave-payloads; merge (per wave, redundant) ====
    float ssum; int pick;
    {
      u64 P0, P1;
      int guard = 0;
      const unsigned tg = (unsigned)(t + 1);
      while (true) {
        P0 = alu64(&pk0[lane]);
        P1 = alu64(&pk1[lane]);
        bool ok = ((unsigned)(P0 & 0xffu) == tg) && ((unsigned)(P1 & 0xffu) == tg);
        if (__ballot(ok) == ~0ull) break;
        __builtin_amdgcn_s_sleep(1);
        if (++guard > (1 << 20)) break;
      }
      float sb = __uint_as_float((unsigned)(P0 >> 32));
      float bm = __uint_as_float((unsigned)(P1 >> 32));
      int bi = (int)((P1 >> 8) & 0x3FFFu);
      #pragma unroll
      for (int m = 1; m <= 32; m <<= 1) {
        sb += __shfl_xor(sb, m);
        const float om = __shfl_xor(bm, m);
        const int oi = __shfl_xor(bi, m);
        if (om > bm || (om == bm && oi < bi)) { bm = om; bi = oi; }
      }
      ssum = sb; pick = bi;
    }
    const int act = active;
    const int valid = (ssum != 0.f) ? 1 : 0;
    {  // row write
      v2f r2;
      if (act && valid) { r2.x = v0 / ssum; r2.y = v1 / ssum; }
      else { r2.x = 0.f; r2.y = 0.f; }
      __builtin_nontemporal_store(r2, (v2f*)(p.out + (size_t)t * N_ENT + (bid << 9) + 2 * tid));
    }
    // ==== centered selection + hit logic (per wave, redundant) ====
    {
      const float kv = keys[(size_t)l32 * N_ENT + pick];
      float mn = kv;
      #pragma unroll
      for (int m = 1; m <= 16; m <<= 1) mn += __shfl_xor(mn, m);
      mn *= (1.f / 32.f);
      const float cv = kv - mn;
      const int nanfree = (__ballot(cv != cv) == 0ull) ? 1 : 0;
      const float em = p.emask[pick];
      const int ol = pick >> 7, bi = pick & 127;
      const u64 wb0 = shfl_u64(pb0, ol), wb1 = shfl_u64(pb1, ol);
      const int prev = (int)(((bi < 64 ? wb0 : wb1) >> (bi & 63)) & 1ull);
      const int hit = (act && valid && (em != 0.f) && !prev) ? 1 : 0;
      if (hit && lane == ol) {
        if (bi < 64) pb0 |= (1ull << bi); else pb1 |= (1ull << (bi & 63));
      }
      if (hit && !nanfree) done = 1;
      active = done ? 0 : 1;
      // ar-slice update: lane l owns ar[bid*64+l]
      float dl = ba3_reg;
      #pragma unroll
      for (int c = 0; c < 32; ++c) dl += wa3s[lane * 33 + c] * __shfl(cv, c);
      if (hit && nanfree) ar_reg += fmaxf(dl, 0.f);
    }
    // ==== next i0 partial + flag ====
    if (t + 1 < steps) {
      float part = 0.f;
      #pragma unroll
      for (int i = 0; i < 64; ++i) part += w0f[i] * __shfl(ar_reg, i);
      st_af(&i0p[tid * 16 + bid], part);
      if (lane == 0)
        __hip_atomic_store(&flagA[bid * 4 + wv], t + 2, __ATOMIC_RELEASE, __HIP_MEMORY_SCOPE_AGENT);
    }
  }

  // ==== epilogue ====
  if (tid < 64) p.out[NN + N_ENT + bid * ARB + tid] = ar_reg;  // wave0's ar slice
  if (bid == 0) {
    if (wv == 0) {
      pb_lds[lane * 4 + 0] = (unsigned)(pb0 & 0xffffffffu);
      pb_lds[lane * 4 + 1] = (unsigned)(pb0 >> 32);
      pb_lds[lane * 4 + 2] = (unsigned)(pb1 & 0xffffffffu);
      pb_lds[lane * 4 + 3] = (unsigned)(pb1 >> 32);
    }
    __syncthreads();
    for (int i = tid; i < N_ENT; i += 256)
      p.out[NN + i] = (float)((pb_lds[i >> 5] >> (i & 31)) & 1u);
  }
}

extern "C" void kernel_launch(void* const* d_in, const int* in_sizes, int n_in,
                              void* d_out, int out_size, void* d_ws, size_t ws_size,
                              hipStream_t stream) {
  (void)in_sizes; (void)n_in; (void)out_size; (void)ws_size;
  Params p;
  p.um    = (const float*)d_in[0];
  p.emask = (const float*)d_in[1];
  p.enc   = (const float*)d_in[2];
  p.arin  = (const float*)d_in[3];
  p.W_fe  = (const float*)d_in[4];
  p.b_fe  = (const float*)d_in[5];
  p.W_k   = (const float*)d_in[6];
  p.b_k   = (const float*)d_in[7];
  p.W_a0  = (const float*)d_in[8];
  p.b_a0  = (const float*)d_in[9];
  p.W_a1  = (const float*)d_in[10];
  p.b_a1  = (const float*)d_in[11];
  p.W_f   = (const float*)d_in[12];
  p.b_f   = (const float*)d_in[13];
  p.W_i0  = (const float*)d_in[14];
  p.b_i0  = (const float*)d_in[15];
  p.W_i1  = (const float*)d_in[16];
  p.b_i1  = (const float*)d_in[17];
  p.W_o   = (const float*)d_in[18];
  p.b_o   = (const float*)d_in[19];
  p.ln_g  = (const float*)d_in[20];
  p.ln_b  = (const float*)d_in[21];
  p.W_a3  = (const float*)d_in[22];
  p.b_a3  = (const float*)d_in[23];
  p.ct    = (const int*)d_in[24];
  p.out   = (float*)d_out;
  p.wsf   = (float*)d_ws;
  p.wsi   = (int*)d_ws;

  hipLaunchKernelGGL(k_init, dim3(NBLK), dim3(256), 0, stream, p);
  hipLaunchKernelGGL(k_scan, dim3(NBLK), dim3(256), 0, stream, p);
}

// Round 5
// 1065.143 us; speedup vs baseline: 1.1219x; 1.1219x over previous
//
#include <hip/hip_runtime.h>
#include <math.h>

// BWNet scan R4 "skinny exchange": 16 scan blocks, 2 rendezvous/step.
// Each block holds FULL ar (LDS) + full W_a3 (LDS) + own 16 W_a0 rows (regs),
// so the ONLY cross-block traffic is: 16 finished i0 rows (1 line) + 1 u64x2
// pick payload per block, all tagged/flagged, read via sc1 atomic loads.
// No acquire-invalidates; read-only data stays cached. One wave polls with
// backoff. Blocks 16..255 zero unit_logits rows [steps..8192) concurrently.

typedef float v4f __attribute__((ext_vector_type(4)));
typedef float v2f __attribute__((ext_vector_type(2)));
typedef unsigned long long u64;

#define N_ENT 8192
#define EMB   256
#define KD    32
#define ARD   1024
#define UT    233
#define NSCAN 16
#define NZBLK 240
#define NBLK  256
#define CPB   512   // key columns per scan block

// float-index offsets into d_ws
#define WS_KEYS  0        // 32*8192, k-major
#define WS_C0    262144   // 256: b_a0 + relu(W_fe@um + b_fe)
#define WS_I0PUB 262400   // 256 floats: finished i0 rows [b*16+j]
#define WS_PK0   262656   // 16 u64 (sum|tag)        (u64 idx)
#define WS_PK1   262720   // 16 u64 (max|idx<<8|tag)
// int-index offsets
#define WS_IFLG  525568   // 16 ints, i0 flags (one 64B line)

struct Params {
  const float *um, *emask, *enc, *arin, *W_fe, *b_fe, *W_k, *b_k,
              *W_a0, *b_a0, *W_a1, *b_a1, *W_f, *b_f, *W_i0, *b_i0,
              *W_i1, *b_i1, *W_o, *b_o, *ln_g, *ln_b, *W_a3, *b_a3;
  const int* ct;
  float* out;
  float* wsf;
  int*   wsi;
};

__device__ __forceinline__ void st_af(float* p, float v) {
  __hip_atomic_store(p, v, __ATOMIC_RELAXED, __HIP_MEMORY_SCOPE_AGENT);
}
__device__ __forceinline__ float alf(float* p) {
  return __hip_atomic_load(p, __ATOMIC_RELAXED, __HIP_MEMORY_SCOPE_AGENT);
}
__device__ __forceinline__ int ali(int* p) {
  return __hip_atomic_load(p, __ATOMIC_RELAXED, __HIP_MEMORY_SCOPE_AGENT);
}
__device__ __forceinline__ u64 alu64(u64* p) {
  return __hip_atomic_load(p, __ATOMIC_RELAXED, __HIP_MEMORY_SCOPE_AGENT);
}
__device__ __forceinline__ u64 shfl_u64(u64 v, int src) {
  int lo = __shfl((int)(unsigned)(v & 0xffffffffu), src);
  int hi = __shfl((int)(unsigned)(v >> 32), src);
  return ((u64)(unsigned)hi << 32) | (u64)(unsigned)lo;
}
__device__ __forceinline__ float ln32(float a, float g, float b) {
  float s = a;
  #pragma unroll
  for (int m = 1; m <= 16; m <<= 1) s += __shfl_xor(s, m);
  const float mean = s * (1.f / 32.f);
  const float d = a - mean;
  float vv = d * d;
  #pragma unroll
  for (int m = 1; m <= 16; m <<= 1) vv += __shfl_xor(vv, m);
  return d * rsqrtf(vv * (1.f / 32.f) + 1e-5f) * g + b;
}

// ---------------- init: keys GEMM (k-major), c0, flag zero ----------------
__global__ __launch_bounds__(256) void k_init(Params p) {
  __shared__ float enc_s[32 * 260];
  __shared__ float um_s[UT];
  const int tid = threadIdx.x, bid = blockIdx.x;
  float* keys = p.wsf + WS_KEYS;

  if (bid == 0 && tid < UT) um_s[tid] = p.um[tid];
  if (bid == 3 && tid < 16) p.wsi[WS_IFLG + tid] = 0;

  const int j0 = bid * 32;
  #pragma unroll
  for (int i = 0; i < 8; ++i) {
    int idx = i * 256 + tid;
    int row = idx >> 6, c4 = idx & 63;
    v4f v = *(const v4f*)(p.enc + (size_t)(j0 + row) * EMB + c4 * 4);
    *(v4f*)&enc_s[row * 260 + c4 * 4] = v;
  }
  __syncthreads();
  {
    const int jl = tid >> 3, kg = tid & 7;
    float acc[4];
    #pragma unroll
    for (int kk = 0; kk < 4; ++kk) acc[kk] = p.b_k[kg * 4 + kk];
    for (int e4 = 0; e4 < 64; ++e4) {
      v4f x = *(const v4f*)&enc_s[jl * 260 + e4 * 4];
      #pragma unroll
      for (int kk = 0; kk < 4; ++kk) {
        v4f w = *(const v4f*)(p.W_k + (size_t)(kg * 4 + kk) * EMB + e4 * 4);
        acc[kk] += x.x * w.x + x.y * w.y + x.z * w.z + x.w * w.w;
      }
    }
    const int j = j0 + jl;
    #pragma unroll
    for (int kk = 0; kk < 4; ++kk) keys[(size_t)(kg * 4 + kk) * N_ENT + j] = acc[kk];
  }
  if (bid == 0) {  // c0 = relu(W_fe@um + b_fe) + b_a0
    float a = p.b_fe[tid];
    const float* wr = p.W_fe + (size_t)tid * UT;
    for (int u = 0; u < UT; ++u) a += wr[u] * um_s[u];
    p.wsf[WS_C0 + tid] = fmaxf(a, 0.f) + p.b_a0[tid];
  }
}

// ---------------- main: scan (blocks 0..15) + zeroing (16..255) ----------------
__global__ __launch_bounds__(256, 1) void k_scan(Params p) {
  const int tid = threadIdx.x, bid = blockIdx.x;
  const int lane = tid & 63, wv = tid >> 6, l32 = lane & 31;
  int ctv = p.ct[0];
  const int steps = ctv < 0 ? 0 : (ctv > 64 ? 64 : ctv);
  const size_t NN = (size_t)N_ENT * N_ENT;

  // LDS (allocated by every block incl. zero-role -> 1 block/CU everywhere)
  __shared__ float wa3_p[1024 * 33];   // 135 KB: full W_a3, row-padded 33
  __shared__ float ar_p[16 * 66];      // full ar, chunk-padded (c*66+off)
  __shared__ float ba3_s[1024];
  __shared__ float ri0_s[8 * 33];
  __shared__ float x_i1[32], q_s[32];
  __shared__ float garr[128], gb_s[128], b_a1s[32];
  __shared__ float i0loc[16], cent_s[32];
  __shared__ float reds[4], rmaxs[4];
  __shared__ int ridxs[4];
  __shared__ float ssum_s;
  __shared__ int act_s, rowact_s, hit_s, nf_s;
  __shared__ unsigned pb_lds[256];

  if (bid >= NSCAN) {  // -------- zero role --------
    v4f z = (v4f){0.f, 0.f, 0.f, 0.f};
    v4f* o4 = (v4f*)p.out;
    const size_t tot = NN / 4;
    for (size_t i = (size_t)steps * (N_ENT / 4) + (size_t)(bid - NSCAN) * 256 + tid;
         i < tot; i += (size_t)NZBLK * 256)
      __builtin_nontemporal_store(z, o4 + i);
    return;
  }

  float* keys  = p.wsf + WS_KEYS;
  float* i0pub = p.wsf + WS_I0PUB;
  u64*   pk0   = (u64*)(p.wsf + WS_PK0);
  u64*   pk1   = (u64*)(p.wsf + WS_PK1);
  int*   iflg  = p.wsi + WS_IFLG;

  // ---- registers ----
  const float lngr = p.ln_g[l32], lnbr = p.ln_b[l32];
  float h_reg = 0.f, q_reg = 0.f;
  u64 pb0 = 0ull, pb1 = 0ull;  // wave0: picked bits, lane l owns [l*128,+128)
  const int rloc = tid >> 4, chk = tid & 15;  // i0 row-local / ar chunk
  const float c0own = (lane < 16) ? p.wsf[WS_C0 + bid * 16 + lane] : 0.f;

  float w0f[64];  // W_a0[bid*16+rloc][chk*64 .. +64)
  {
    const v4f* s = (const v4f*)(p.W_a0 + (size_t)(bid * 16 + rloc) * ARD + chk * 64);
    #pragma unroll
    for (int i = 0; i < 16; ++i) {
      v4f v = s[i];
      w0f[4*i] = v.x; w0f[4*i+1] = v.y; w0f[4*i+2] = v.z; w0f[4*i+3] = v.w;
    }
  }
  // ---- ar into LDS, then initial i0 publish (tag 1) ----
  if (tid < 256) {
    v4f v = *(const v4f*)(p.arin + tid * 4);
    const int e = tid * 4, c = e >> 6, off = e & 63;
    float* d = &ar_p[c * 66 + off];
    d[0] = v.x; d[1] = v.y; d[2] = v.z; d[3] = v.w;
  }
  __syncthreads();
  {
    float part = 0.f;
    #pragma unroll
    for (int j = 0; j < 64; ++j) part += w0f[j] * ar_p[chk * 66 + j];
    #pragma unroll
    for (int m = 1; m <= 8; m <<= 1) part += __shfl_xor(part, m);
    if (chk == 0) i0loc[rloc] = part;
  }
  __syncthreads();
  if (wv == 0 && lane < 16) {
    st_af(&i0pub[bid * 16 + lane], i0loc[lane] + c0own);
    if (lane == 0)
      __hip_atomic_store(&iflg[bid], 1, __ATOMIC_RELEASE, __HIP_MEMORY_SCOPE_AGENT);
  }

  // ---- heavy LDS staging (overlaps others' publishes) ----
  for (int d = tid; d < 1024; d += 256) {  // W_a3 full, padded
    const v4f* s = (const v4f*)(p.W_a3 + (size_t)d * KD);
    float* dst = &wa3_p[d * 33];
    #pragma unroll
    for (int i = 0; i < 8; ++i) {
      v4f v = s[i];
      dst[4*i] = v.x; dst[4*i+1] = v.y; dst[4*i+2] = v.z; dst[4*i+3] = v.w;
    }
    ba3_s[d] = p.b_a3[d];
  }
  v4f w1[8];
  { const float* s = p.W_a1 + (size_t)(tid >> 3) * EMB + (tid & 7) * 32;
    #pragma unroll
    for (int i = 0; i < 8; ++i) w1[i] = ((const v4f*)s)[i]; }
  v4f wg[8];
  { const int rowg = tid >> 1, g = rowg >> 5, r = rowg & 31, half = tid & 1;
    const float* W = (g == 0) ? p.W_f : (g == 1) ? p.W_i0 : (g == 2) ? p.W_i1 : p.W_o;
    const float* s = W + r * 64 + half * 32;
    #pragma unroll
    for (int i = 0; i < 8; ++i) wg[i] = ((const v4f*)s)[i]; }
  if (tid < 32) { b_a1s[tid] = p.b_a1[tid]; q_s[tid] = 0.f; }
  if (tid < 128) {
    const int g = tid >> 5, r = tid & 31;
    const float* bg = (g == 0) ? p.b_f : (g == 1) ? p.b_i0 : (g == 2) ? p.b_i1 : p.b_o;
    gb_s[tid] = bg[r];
  }
  if (tid == 0) { act_s = 1; rowact_s = 1; hit_s = 0; nf_s = 1; }
  const float* kbase = keys + bid * CPB + 2 * tid;
  __syncthreads();

  int done = 0;  // wave0 lane-uniform scalar
  for (int t = 0; t < steps; ++t) {
    const int tg = t + 1;
    // ==== wait i0 flags (wave0 polls, backoff) ====
    if (wv == 0) {
      int guard = 0;
      while (true) {
        int f = (lane < 16) ? ali(&iflg[lane]) : tg;
        if (__ballot(f == tg) == ~0ull) break;
        __builtin_amdgcn_s_sleep(2);
        if (++guard > (1 << 20)) break;
      }
    }
    __syncthreads();  // S_A
    // ==== read finished i0 rows (sc1, coalesced) ====
    ri0_s[(tid >> 5) * 33 + (tid & 31)] = fmaxf(alf(&i0pub[tid]), 0.f);
    __syncthreads();  // S_B
    {  // i1 = relu(W_a1 @ ri0 + b_a1)
      const int r = tid >> 3, s8 = tid & 7;
      float p1 = 0.f;
      #pragma unroll
      for (int i = 0; i < 8; ++i) {
        const float* xx = &ri0_s[s8 * 33 + 4 * i];
        p1 += w1[i].x * xx[0] + w1[i].y * xx[1] + w1[i].z * xx[2] + w1[i].w * xx[3];
      }
      #pragma unroll
      for (int m = 4; m; m >>= 1) p1 += __shfl_xor(p1, m);
      if (s8 == 0) x_i1[r] = fmaxf(p1 + b_a1s[r], 0.f);
    }
    __syncthreads();  // S_C
    {  // 4 LSTM gate matvecs
      const int rowg = tid >> 1, g = rowg >> 5, half = tid & 1;
      const float* xsrc = half ? q_s : x_i1;
      float pg = 0.f;
      #pragma unroll
      for (int i = 0; i < 8; ++i)
        pg += wg[i].x * xsrc[4 * i] + wg[i].y * xsrc[4 * i + 1] +
              wg[i].z * xsrc[4 * i + 2] + wg[i].w * xsrc[4 * i + 3];
      pg += __shfl_xor(pg, 1);
      if (!half) {
        pg += gb_s[rowg];
        garr[rowg] = (g == 2) ? tanhf(pg) : 1.f / (1.f + __expf(-pg));
      }
    }
    __syncthreads();  // S_D
    // ==== per-wave redundant: LNs, qn, state gate ====
    float qn;
    {
      const int act = act_s;
      const float f = ln32(garr[l32], lngr, lnbr);
      const float rm = ln32(garr[32 + l32] * garr[64 + l32], lngr, lnbr);
      const float o = ln32(garr[96 + l32], lngr, lnbr);
      const float nh = rm + f * h_reg;
      const float qv = tanhf(nh) * o;
      qn = qv;
      if (act) { h_reg = nh; q_reg = qv; }
      if (tid < 32) q_s[tid] = q_reg;  // consumed after next step's S_C
    }
    // ==== sweep own 512 cols (streamed from L2) ====
    float v0, v1;
    {
      float d0 = 0.f, d1 = 0.f;
      #pragma unroll
      for (int k = 0; k < 32; ++k) {
        const float qk = __shfl(qn, k);
        const v2f kk = *(const v2f*)(kbase + (size_t)k * N_ENT);
        d0 += qk * kk.x; d1 += qk * kk.y;
      }
      const float s0 = 1.f / (1.f + __expf(-d0));
      const float s1 = 1.f / (1.f + __expf(-d1));
      v0 = __expf(__logf(s0) * 1.25f);
      v1 = __expf(__logf(s1) * 1.25f);
      float sv = v0 + v1;
      float mv; int mi;
      const int gi0 = (bid << 9) + 2 * tid;
      if (v1 > v0) { mv = v1; mi = gi0 + 1; } else { mv = v0; mi = gi0; }
      #pragma unroll
      for (int m = 1; m <= 32; m <<= 1) {
        sv += __shfl_xor(sv, m);
        const float om = __shfl_xor(mv, m);
        const int oi = __shfl_xor(mi, m);
        if (om > mv || (om == mv && oi < mi)) { mv = om; mi = oi; }
      }
      if ((lane & 63) == 0) { reds[wv] = sv; rmaxs[wv] = mv; ridxs[wv] = mi; }
    }
    __syncthreads();  // S_E
    // ==== wave0: merge block partial, publish, poll, global merge, pick logic ====
    if (wv == 0) {
      if (lane == 0) {
        float S = ((reds[0] + reds[1]) + reds[2]) + reds[3];
        float M = rmaxs[0]; int I = ridxs[0];
        #pragma unroll
        for (int i2 = 1; i2 < 4; ++i2)
          if (rmaxs[i2] > M || (rmaxs[i2] == M && ridxs[i2] < I)) { M = rmaxs[i2]; I = ridxs[i2]; }
        const u64 tg8 = (u64)(unsigned)tg;
        __hip_atomic_store(&pk0[bid], ((u64)__float_as_uint(S) << 32) | tg8,
                           __ATOMIC_RELAXED, __HIP_MEMORY_SCOPE_AGENT);
        __hip_atomic_store(&pk1[bid], ((u64)__float_as_uint(M) << 32) | ((u64)(unsigned)I << 8) | tg8,
                           __ATOMIC_RELAXED, __HIP_MEMORY_SCOPE_AGENT);
      }
      // poll all 16 tagged payloads (lanes<16)
      u64 P0 = 0, P1 = 0;
      {
        int guard = 0;
        while (true) {
          bool ok = true;
          if (lane < 16) {
            P0 = alu64(&pk0[lane]);
            P1 = alu64(&pk1[lane]);
            ok = ((unsigned)(P0 & 0xffu) == (unsigned)tg) && ((unsigned)(P1 & 0xffu) == (unsigned)tg);
          }
          if (__ballot(ok) == ~0ull) break;
          __builtin_amdgcn_s_sleep(2);
          if (++guard > (1 << 20)) break;
        }
      }
      float sb = (lane < 16) ? __uint_as_float((unsigned)(P0 >> 32)) : 0.f;
      float bm = (lane < 16) ? __uint_as_float((unsigned)(P1 >> 32)) : -1.f;
      int bi = (lane < 16) ? (int)((P1 >> 8) & 0x3FFFu) : N_ENT;
      #pragma unroll
      for (int m = 1; m <= 8; m <<= 1) {
        sb += __shfl_xor(sb, m);
        const float om = __shfl_xor(bm, m);
        const int oi = __shfl_xor(bi, m);
        if (om > bm || (om == bm && oi < bi)) { bm = om; bi = oi; }
      }
      const float ssum = __shfl(sb, 0);
      const int pick = __shfl(bi, 0);
      // cent (lanes<32), nanfree
      float cv = 0.f;
      if (lane < 32) {
        const float kv = keys[(size_t)l32 * N_ENT + pick];
        float mn = kv;
        #pragma unroll
        for (int m = 1; m <= 16; m <<= 1) mn += __shfl_xor(mn, m);
        cv = kv - mn * (1.f / 32.f);
        cent_s[l32] = cv;
      }
      const int nanfree = (__ballot(lane < 32 ? (cv != cv) : false) == 0ull) ? 1 : 0;
      // hit logic (lane-uniform via shfl/ballot)
      const int act = act_s;
      const int valid = (ssum != 0.f) ? 1 : 0;
      const float em = p.emask[pick];
      const int ol = pick >> 7, bit = pick & 127;
      const u64 wb0 = shfl_u64(pb0, ol), wb1 = shfl_u64(pb1, ol);
      const int prev = (int)(((bit < 64 ? wb0 : wb1) >> (bit & 63)) & 1ull);
      const int hit = (act && valid && (em != 0.f) && !prev) ? 1 : 0;
      if (hit && lane == ol) {
        if (bit < 64) pb0 |= (1ull << bit); else pb1 |= (1ull << (bit & 63));
      }
      if (hit && !nanfree) done = 1;
      if (lane == 0) {
        ssum_s = ssum;
        rowact_s = act && valid;
        hit_s = hit; nf_s = nanfree;
        act_s = done ? 0 : 1;
      }
    }
    __syncthreads();  // S_F
    // ==== all: row write + delta/ar update ====
    {
      v2f r2;
      if (rowact_s) { const float inv = 1.f / ssum_s; r2.x = v0 * inv; r2.y = v1 * inv; }
      else { r2.x = 0.f; r2.y = 0.f; }
      __builtin_nontemporal_store(r2, (v2f*)(p.out + (size_t)t * N_ENT + (bid << 9) + 2 * tid));
    }
    if (hit_s && nf_s) {
      #pragma unroll
      for (int i = 0; i < 4; ++i) {
        const int d = tid * 4 + i;
        float dl = ba3_s[d];
        const float* wr = &wa3_p[d * 33];
        #pragma unroll
        for (int c = 0; c < 32; ++c) dl += wr[c] * cent_s[c];
        ar_p[(d >> 6) * 66 + (d & 63)] += fmaxf(dl, 0.f);
      }
    }
    __syncthreads();  // S_G
    // ==== all: own i0 rows from full ar; publish ====
    if (t + 1 < steps) {
      float part = 0.f;
      #pragma unroll
      for (int j = 0; j < 64; ++j) part += w0f[j] * ar_p[chk * 66 + j];
      #pragma unroll
      for (int m = 1; m <= 8; m <<= 1) part += __shfl_xor(part, m);
      if (chk == 0) i0loc[rloc] = part;
      __syncthreads();  // S_H
      if (wv == 0 && lane < 16) {
        st_af(&i0pub[bid * 16 + lane], i0loc[lane] + c0own);
        if (lane == 0)
          __hip_atomic_store(&iflg[bid], t + 2, __ATOMIC_RELEASE, __HIP_MEMORY_SCOPE_AGENT);
      }
    }
  }

  // ==== epilogue ====
  if (bid == 0) {
    if (wv == 0) {
      pb_lds[lane * 4 + 0] = (unsigned)(pb0 & 0xffffffffu);
      pb_lds[lane * 4 + 1] = (unsigned)(pb0 >> 32);
      pb_lds[lane * 4 + 2] = (unsigned)(pb1 & 0xffffffffu);
      pb_lds[lane * 4 + 3] = (unsigned)(pb1 >> 32);
    }
    __syncthreads();
    for (int i = tid; i < N_ENT; i += 256)
      p.out[NN + i] = (float)((pb_lds[i >> 5] >> (i & 31)) & 1u);
    {  // ar_out from local full copy
      const int e = tid * 4;
      const float* s = &ar_p[(e >> 6) * 66 + (e & 63)];
      float* d = p.out + NN + N_ENT + e;
      d[0] = s[0]; d[1] = s[1]; d[2] = s[2]; d[3] = s[3];
    }
  }
}

extern "C" void kernel_launch(void* const* d_in, const int* in_sizes, int n_in,
                              void* d_out, int out_size, void* d_ws, size_t ws_size,
                              hipStream_t stream) {
  (void)in_sizes; (void)n_in; (void)out_size; (void)ws_size;
  Params p;
  p.um    = (const float*)d_in[0];
  p.emask = (const float*)d_in[1];
  p.enc   = (const float*)d_in[2];
  p.arin  = (const float*)d_in[3];
  p.W_fe  = (const float*)d_in[4];
  p.b_fe  = (const float*)d_in[5];
  p.W_k   = (const float*)d_in[6];
  p.b_k   = (const float*)d_in[7];
  p.W_a0  = (const float*)d_in[8];
  p.b_a0  = (const float*)d_in[9];
  p.W_a1  = (const float*)d_in[10];
  p.b_a1  = (const float*)d_in[11];
  p.W_f   = (const float*)d_in[12];
  p.b_f   = (const float*)d_in[13];
  p.W_i0  = (const float*)d_in[14];
  p.b_i0  = (const float*)d_in[15];
  p.W_i1  = (const float*)d_in[16];
  p.b_i1  = (const float*)d_in[17];
  p.W_o   = (const float*)d_in[18];
  p.b_o   = (const float*)d_in[19];
  p.ln_g  = (const float*)d_in[20];
  p.ln_b  = (const float*)d_in[21];
  p.W_a3  = (const float*)d_in[22];
  p.b_a3  = (const float*)d_in[23];
  p.ct    = (const int*)d_in[24];
  p.out   = (float*)d_out;
  p.wsf   = (float*)d_ws;
  p.wsi   = (int*)d_ws;

  hipLaunchKernelGGL(k_init, dim3(NBLK), dim3(256), 0, stream, p);
  hipLaunchKernelGGL(k_scan, dim3(NBLK), dim3(256), 0, stream, p);
}

// Round 6
// 1048.730 us; speedup vs baseline: 1.1395x; 1.0157x over previous
//
#include <hip/hip_runtime.h>
#include <math.h>

// BWNet scan R5: 8 scan blocks, 2 skinny rendezvous/step, light per-block work.
// Block b owns: 1024 key cols (LDS), W_a0 col-slice [128b,+128) x 256 rows (VGPRs),
// W_a3 row-slice + ar slice (LDS). Cross-block traffic per step: 8x256-float i0
// partials (flag-released, acquire+plain-load = R1-proven) + 8 tagged u64 pick
// payloads (relaxed sc1 = R4-proven). Row-write moved off the critical path.
// Blocks 8..255 zero unit_logits rows [steps..8192) concurrently.

typedef float v4f __attribute__((ext_vector_type(4)));
typedef unsigned long long u64;

#define N_ENT 8192
#define EMB   256
#define KD    32
#define ARD   1024
#define UT    233
#define NSCAN 8
#define NBLK  256
#define CPB   1024  // key columns per scan block
#define ARB   128   // ar-slice length per scan block

// float-index offsets into d_ws
#define WS_KEYS  0        // 32*8192, k-major
#define WS_C0    262144   // 256: b_a0 + relu(W_fe@um + b_fe)
#define WS_I0PUB 262400   // 8*256 floats [b*256+e]
#define WS_PK0   264448   // 8 u64 (sum<<32 | tag)
#define WS_PK1   264464   // 8 u64 (max<<32 | idx<<8 | tag)
// int-index offsets
#define WS_IFLG  264480   // 8 ints

struct Params {
  const float *um, *emask, *enc, *arin, *W_fe, *b_fe, *W_k, *b_k,
              *W_a0, *b_a0, *W_a1, *b_a1, *W_f, *b_f, *W_i0, *b_i0,
              *W_i1, *b_i1, *W_o, *b_o, *ln_g, *ln_b, *W_a3, *b_a3;
  const int* ct;
  float* out;
  float* wsf;
  int*   wsi;
};

__device__ __forceinline__ void st_af(float* p, float v) {
  __hip_atomic_store(p, v, __ATOMIC_RELAXED, __HIP_MEMORY_SCOPE_AGENT);
}
__device__ __forceinline__ int ali(int* p) {
  return __hip_atomic_load(p, __ATOMIC_RELAXED, __HIP_MEMORY_SCOPE_AGENT);
}
__device__ __forceinline__ u64 alu64(u64* p) {
  return __hip_atomic_load(p, __ATOMIC_RELAXED, __HIP_MEMORY_SCOPE_AGENT);
}
__device__ __forceinline__ u64 shfl_u64(u64 v, int src) {
  int lo = __shfl((int)(unsigned)(v & 0xffffffffu), src);
  int hi = __shfl((int)(unsigned)(v >> 32), src);
  return ((u64)(unsigned)hi << 32) | (u64)(unsigned)lo;
}
__device__ __forceinline__ float ln32(float a, float g, float b) {
  float s = a;
  #pragma unroll
  for (int m = 1; m <= 16; m <<= 1) s += __shfl_xor(s, m);
  const float mean = s * (1.f / 32.f);
  const float d = a - mean;
  float vv = d * d;
  #pragma unroll
  for (int m = 1; m <= 16; m <<= 1) vv += __shfl_xor(vv, m);
  return d * rsqrtf(vv * (1.f / 32.f) + 1e-5f) * g + b;
}

// ---------------- init: keys GEMM (k-major), c0 ----------------
__global__ __launch_bounds__(256) void k_init(Params p) {
  __shared__ float enc_s[32 * 260];
  __shared__ float um_s[UT];
  const int tid = threadIdx.x, bid = blockIdx.x;
  float* keys = p.wsf + WS_KEYS;

  if (bid == 0 && tid < UT) um_s[tid] = p.um[tid];

  const int j0 = bid * 32;
  #pragma unroll
  for (int i = 0; i < 8; ++i) {
    int idx = i * 256 + tid;
    int row = idx >> 6, c4 = idx & 63;
    v4f v = *(const v4f*)(p.enc + (size_t)(j0 + row) * EMB + c4 * 4);
    *(v4f*)&enc_s[row * 260 + c4 * 4] = v;
  }
  __syncthreads();
  {
    const int jl = tid >> 3, kg = tid & 7;
    float acc[4];
    #pragma unroll
    for (int kk = 0; kk < 4; ++kk) acc[kk] = p.b_k[kg * 4 + kk];
    for (int e4 = 0; e4 < 64; ++e4) {
      v4f x = *(const v4f*)&enc_s[jl * 260 + e4 * 4];
      #pragma unroll
      for (int kk = 0; kk < 4; ++kk) {
        v4f w = *(const v4f*)(p.W_k + (size_t)(kg * 4 + kk) * EMB + e4 * 4);
        acc[kk] += x.x * w.x + x.y * w.y + x.z * w.z + x.w * w.w;
      }
    }
    const int j = j0 + jl;
    #pragma unroll
    for (int kk = 0; kk < 4; ++kk) keys[(size_t)(kg * 4 + kk) * N_ENT + j] = acc[kk];
  }
  if (bid == 0) {  // c0 = relu(W_fe@um + b_fe) + b_a0
    float a = p.b_fe[tid];
    const float* wr = p.W_fe + (size_t)tid * UT;
    for (int u = 0; u < UT; ++u) a += wr[u] * um_s[u];
    p.wsf[WS_C0 + tid] = fmaxf(a, 0.f) + p.b_a0[tid];
  }
}

// ---------------- main: scan (blocks 0..7) + zeroing (8..255) ----------------
__global__ __launch_bounds__(256, 1) void k_scan(Params p) {
  const int tid = threadIdx.x, bid = blockIdx.x;
  const int lane = tid & 63, wv = tid >> 6, l32 = lane & 31;
  int ctv = p.ct[0];
  const int steps = ctv < 0 ? 0 : (ctv > 64 ? 64 : ctv);
  const size_t NN = (size_t)N_ENT * N_ENT;

  __shared__ __align__(16) float kslice[KD * CPB];  // 128 KB
  __shared__ __align__(16) float wa3s[ARB * 33];    // 16.9 KB, 2-way-free pad
  __shared__ __align__(16) float ar_s[ARB];
  __shared__ __align__(16) float ri0_s[8 * 33];
  __shared__ __align__(16) float qb_s[32];
  __shared__ float x_i1[32], q_s[32];
  __shared__ float garr[128], gb_s[128], b_a1s[32], ba3_sl[ARB], cent_s[32];
  __shared__ float reds[4], rmaxs[4];
  __shared__ int ridxs[4];
  __shared__ float rowinv_s;
  __shared__ int act_s, hit_s, nf_s;
  __shared__ unsigned pb_lds[256];

  if (bid >= NSCAN) {  // -------- zero role --------
    v4f z = (v4f){0.f, 0.f, 0.f, 0.f};
    v4f* o4 = (v4f*)p.out;
    const size_t tot = NN / 4;
    for (size_t i = (size_t)steps * (N_ENT / 4) + (size_t)(bid - NSCAN) * 256 + tid;
         i < tot; i += (size_t)(NBLK - NSCAN) * 256)
      __builtin_nontemporal_store(z, o4 + i);
    return;
  }

  float* keys  = p.wsf + WS_KEYS;
  float* i0pub = p.wsf + WS_I0PUB;
  u64*   pk0   = (u64*)(p.wsf + WS_PK0);
  u64*   pk1   = (u64*)(p.wsf + WS_PK1);
  int*   iflg  = p.wsi + WS_IFLG;

  const float lngr = p.ln_g[l32], lnbr = p.ln_b[l32];
  float h_reg = 0.f, q_reg = 0.f;
  u64 pb0 = 0ull, pb1 = 0ull;  // wave0 picked bits: lane l owns [l*128,+128)
  const float c0r = p.wsf[WS_C0 + tid];

  // W_a0 row tid, cols [bid*128, +128) -> 128 VGPRs (1 wave/SIMD: fine)
  float w0f[ARB];
  {
    const v4f* s = (const v4f*)(p.W_a0 + (size_t)tid * ARD + bid * ARB);
    #pragma unroll
    for (int i = 0; i < 32; ++i) {
      v4f v = s[i];
      w0f[4*i] = v.x; w0f[4*i+1] = v.y; w0f[4*i+2] = v.z; w0f[4*i+3] = v.w;
    }
  }
  // ar slice + initial i0 partial publish (tag 1) ASAP
  if (tid < ARB) ar_s[tid] = p.arin[bid * ARB + tid];
  __syncthreads();
  {
    float part = 0.f;
    const v4f* a4 = (const v4f*)ar_s;
    #pragma unroll
    for (int i = 0; i < 32; ++i) {
      v4f av = a4[i];
      part += w0f[4*i] * av.x + w0f[4*i+1] * av.y + w0f[4*i+2] * av.z + w0f[4*i+3] * av.w;
    }
    st_af(&i0pub[bid * 256 + tid], part);
  }
  __syncthreads();  // drain vmcnt before flag release
  if (tid == 0)
    __hip_atomic_store(&iflg[bid], 1, __ATOMIC_RELEASE, __HIP_MEMORY_SCOPE_AGENT);

  // ---- heavy staging (overlaps other blocks' publishes) ----
  for (int i4 = tid; i4 < KD * (CPB / 4); i4 += 256) {  // kslice
    int k = i4 >> 8, c4 = i4 & 255;
    v4f v = *(const v4f*)(keys + (size_t)k * N_ENT + bid * CPB + c4 * 4);
    *(v4f*)&kslice[k * CPB + c4 * 4] = v;
  }
  for (int r = tid; r < ARB; r += 256) {  // W_a3 slice rows [128b,+128)
    const v4f* s = (const v4f*)(p.W_a3 + (size_t)(bid * ARB + r) * KD);
    float* dst = &wa3s[r * 33];
    #pragma unroll
    for (int i = 0; i < 8; ++i) {
      v4f v = s[i];
      dst[4*i] = v.x; dst[4*i+1] = v.y; dst[4*i+2] = v.z; dst[4*i+3] = v.w;
    }
    ba3_sl[r] = p.b_a3[bid * ARB + r];
  }
  float w1r[32];  // W_a1 row tid>>3, cols (tid&7)*32..+32
  { const v4f* s = (const v4f*)(p.W_a1 + (size_t)(tid >> 3) * EMB + (tid & 7) * 32);
    #pragma unroll
    for (int i = 0; i < 8; ++i) {
      v4f v = s[i];
      w1r[4*i] = v.x; w1r[4*i+1] = v.y; w1r[4*i+2] = v.z; w1r[4*i+3] = v.w;
    } }
  float wgr[32];  // LSTM gate row tid>>1, half tid&1
  { const int rowg = tid >> 1, g = rowg >> 5, r = rowg & 31, half = tid & 1;
    const float* W = (g == 0) ? p.W_f : (g == 1) ? p.W_i0 : (g == 2) ? p.W_i1 : p.W_o;
    const v4f* s = (const v4f*)(W + r * 64 + half * 32);
    #pragma unroll
    for (int i = 0; i < 8; ++i) {
      v4f v = s[i];
      wgr[4*i] = v.x; wgr[4*i+1] = v.y; wgr[4*i+2] = v.z; wgr[4*i+3] = v.w;
    } }
  if (tid < 32) { b_a1s[tid] = p.b_a1[tid]; q_s[tid] = 0.f; }
  if (tid < 128) {
    const int g = tid >> 5, r = tid & 31;
    const float* bg = (g == 0) ? p.b_f : (g == 1) ? p.b_i0 : (g == 2) ? p.b_i1 : p.b_o;
    gb_s[tid] = bg[r];
  }
  if (tid == 0) { act_s = 1; hit_s = 0; nf_s = 1; rowinv_s = 0.f; }
  __syncthreads();

  int done = 0;  // wave0 lane-uniform
  for (int t = 0; t < steps; ++t) {
    const int tg = t + 1;
    // ==== RV1: wait i0 flags, acquire, gather+sum partials ====
    if (wv == 0) {
      int guard = 0;
      while (true) {
        int f = (lane < NSCAN) ? ali(&iflg[lane]) : tg;
        if (__ballot(f == tg) == ~0ull) break;
        __builtin_amdgcn_s_sleep(1);
        if (++guard > (1 << 20)) break;
      }
      if (lane == 0)
        (void)__hip_atomic_load(&iflg[0], __ATOMIC_ACQUIRE, __HIP_MEMORY_SCOPE_AGENT);
    }
    __syncthreads();
    {
      float acc = c0r;
      #pragma unroll
      for (int b2 = 0; b2 < NSCAN; ++b2) acc += i0pub[b2 * 256 + tid];  // plain, coalesced
      ri0_s[(tid >> 5) * 33 + (tid & 31)] = fmaxf(acc, 0.f);
    }
    __syncthreads();
    {  // i1 = relu(W_a1 @ ri0 + b_a1)
      const int r = tid >> 3, s8 = tid & 7;
      float p1 = 0.f;
      #pragma unroll
      for (int i = 0; i < 32; ++i) p1 += w1r[i] * ri0_s[s8 * 33 + i];
      #pragma unroll
      for (int m = 4; m; m >>= 1) p1 += __shfl_xor(p1, m);
      if (s8 == 0) x_i1[r] = fmaxf(p1 + b_a1s[r], 0.f);
    }
    __syncthreads();
    {  // 4 LSTM gate matvecs
      const int rowg = tid >> 1, g = rowg >> 5, half = tid & 1;
      const float* xsrc = half ? q_s : x_i1;
      float pg = 0.f;
      #pragma unroll
      for (int i = 0; i < 32; ++i) pg += wgr[i] * xsrc[i];
      pg += __shfl_xor(pg, 1);
      if (!half) {
        pg += gb_s[rowg];
        garr[rowg] = (g == 2) ? tanhf(pg) : 1.f / (1.f + __expf(-pg));
      }
    }
    __syncthreads();
    {  // per-wave redundant: LNs, qn, gated state
      const int act = act_s;
      const float f = ln32(garr[l32], lngr, lnbr);
      const float rm = ln32(garr[32 + l32] * garr[64 + l32], lngr, lnbr);
      const float o = ln32(garr[96 + l32], lngr, lnbr);
      const float nh = rm + f * h_reg;
      const float qv = tanhf(nh) * o;
      if (act) { h_reg = nh; q_reg = qv; }
      if (tid < 32) { qb_s[tid] = qv; q_s[tid] = q_reg; }
    }
    __syncthreads();
    // ==== sweep own 1024 cols (4/thread from LDS) ====
    float vr[4];
    {
      float qf[32];
      { const v4f* q4 = (const v4f*)qb_s;
        #pragma unroll
        for (int i = 0; i < 8; ++i) {
          v4f v = q4[i];
          qf[4*i] = v.x; qf[4*i+1] = v.y; qf[4*i+2] = v.z; qf[4*i+3] = v.w;
        } }
      float d0 = 0.f, d1 = 0.f, d2 = 0.f, d3 = 0.f;
      #pragma unroll
      for (int k = 0; k < 32; ++k) {
        const v4f kk = *(const v4f*)&kslice[k * CPB + 4 * tid];
        const float qk = qf[k];
        d0 += qk * kk.x; d1 += qk * kk.y; d2 += qk * kk.z; d3 += qk * kk.w;
      }
      vr[0] = __expf(__logf(1.f / (1.f + __expf(-d0))) * 1.25f);
      vr[1] = __expf(__logf(1.f / (1.f + __expf(-d1))) * 1.25f);
      vr[2] = __expf(__logf(1.f / (1.f + __expf(-d2))) * 1.25f);
      vr[3] = __expf(__logf(1.f / (1.f + __expf(-d3))) * 1.25f);
      float sv = (vr[0] + vr[1]) + (vr[2] + vr[3]);
      float mv = vr[0]; int mi = bid * CPB + 4 * tid;
      #pragma unroll
      for (int i = 1; i < 4; ++i)
        if (vr[i] > mv) { mv = vr[i]; mi = bid * CPB + 4 * tid + i; }
      #pragma unroll
      for (int m = 1; m <= 32; m <<= 1) {
        sv += __shfl_xor(sv, m);
        const float om = __shfl_xor(mv, m);
        const int oi = __shfl_xor(mi, m);
        if (om > mv || (om == mv && oi < mi)) { mv = om; mi = oi; }
      }
      if (lane == 0) { reds[wv] = sv; rmaxs[wv] = mv; ridxs[wv] = mi; }
    }
    __syncthreads();
    // ==== RV2: wave0 merges block partial, publishes, polls, global merge ====
    if (wv == 0) {
      if (lane == 0) {
        float S = ((reds[0] + reds[1]) + reds[2]) + reds[3];
        float M = rmaxs[0]; int I = ridxs[0];
        #pragma unroll
        for (int i2 = 1; i2 < 4; ++i2)
          if (rmaxs[i2] > M || (rmaxs[i2] == M && ridxs[i2] < I)) { M = rmaxs[i2]; I = ridxs[i2]; }
        const u64 tg8 = (u64)(unsigned)tg;
        __hip_atomic_store(&pk0[bid], ((u64)__float_as_uint(S) << 32) | tg8,
                           __ATOMIC_RELAXED, __HIP_MEMORY_SCOPE_AGENT);
        __hip_atomic_store(&pk1[bid], ((u64)__float_as_uint(M) << 32) | ((u64)(unsigned)I << 8) | tg8,
                           __ATOMIC_RELAXED, __HIP_MEMORY_SCOPE_AGENT);
      }
      u64 P0 = 0, P1 = 0;
      {
        int guard = 0;
        while (true) {
          bool ok = true;
          if (lane < NSCAN) {
            P0 = alu64(&pk0[lane]);
            P1 = alu64(&pk1[lane]);
            ok = ((unsigned)(P0 & 0xffu) == (unsigned)tg) && ((unsigned)(P1 & 0xffu) == (unsigned)tg);
          }
          if (__ballot(ok) == ~0ull) break;
          __builtin_amdgcn_s_sleep(1);
          if (++guard > (1 << 20)) break;
        }
      }
      float sb = (lane < NSCAN) ? __uint_as_float((unsigned)(P0 >> 32)) : 0.f;
      float bm = (lane < NSCAN) ? __uint_as_float((unsigned)(P1 >> 32)) : -1.f;
      int bi = (lane < NSCAN) ? (int)((P1 >> 8) & 0x3FFFu) : N_ENT;
      #pragma unroll
      for (int m = 1; m <= 4; m <<= 1) {
        sb += __shfl_xor(sb, m);
        const float om = __shfl_xor(bm, m);
        const int oi = __shfl_xor(bi, m);
        if (om > bm || (om == bm && oi < bi)) { bm = om; bi = oi; }
      }
      const float ssum = __shfl(sb, 0);
      const int pick = __shfl(bi, 0);
      float cv = 0.f;
      if (lane < 32) {
        const float kv = keys[(size_t)l32 * N_ENT + pick];
        float mn = kv;
        #pragma unroll
        for (int m = 1; m <= 16; m <<= 1) mn += __shfl_xor(mn, m);
        cv = kv - mn * (1.f / 32.f);
        cent_s[l32] = cv;
      }
      const int nanfree = (__ballot(cv != cv) == 0ull) ? 1 : 0;
      const int act = act_s;
      const int valid = (ssum != 0.f) ? 1 : 0;
      const float em = p.emask[pick];
      const int ol = pick >> 7, bit = pick & 127;
      const u64 wb0 = shfl_u64(pb0, ol), wb1 = shfl_u64(pb1, ol);
      const int prev = (int)(((bit < 64 ? wb0 : wb1) >> (bit & 63)) & 1ull);
      const int hit = (act && valid && (em != 0.f) && !prev) ? 1 : 0;
      if (hit && lane == ol) {
        if (bit < 64) pb0 |= (1ull << bit); else pb1 |= (1ull << (bit & 63));
      }
      if (hit && !nanfree) done = 1;
      if (lane == 0) {
        rowinv_s = (act && valid) ? (1.f / ssum) : 0.f;
        hit_s = hit; nf_s = nanfree;
        act_s = done ? 0 : 1;
      }
    }
    __syncthreads();
    // ==== d + ar slice update (2 threads/row, conflict-free) ====
    if (hit_s && nf_s) {
      const int r = tid >> 1, half = tid & 1;
      float dl = 0.f;
      #pragma unroll
      for (int j = 0; j < 16; ++j) dl += wa3s[r * 33 + 16 * half + j] * cent_s[16 * half + j];
      dl += __shfl_xor(dl, 1);
      if (!half) ar_s[r] += fmaxf(dl + ba3_sl[r], 0.f);
    }
    __syncthreads();
    // ==== own i0 partial from ar slice; publish + flag ====
    if (t + 1 < steps) {
      float part = 0.f;
      const v4f* a4 = (const v4f*)ar_s;
      #pragma unroll
      for (int i = 0; i < 32; ++i) {
        v4f av = a4[i];
        part += w0f[4*i] * av.x + w0f[4*i+1] * av.y + w0f[4*i+2] * av.z + w0f[4*i+3] * av.w;
      }
      st_af(&i0pub[bid * 256 + tid], part);
      __syncthreads();  // drain vmcnt
      if (tid == 0)
        __hip_atomic_store(&iflg[bid], t + 2, __ATOMIC_RELEASE, __HIP_MEMORY_SCOPE_AGENT);
    }
    // ==== row write (off critical path) ====
    {
      const float inv = rowinv_s;
      v4f r4 = (v4f){vr[0] * inv, vr[1] * inv, vr[2] * inv, vr[3] * inv};
      __builtin_nontemporal_store(r4, (v4f*)(p.out + (size_t)t * N_ENT + bid * CPB + 4 * tid));
    }
  }

  // ==== epilogue ====
  __syncthreads();
  if (tid < ARB) p.out[NN + N_ENT + bid * ARB + tid] = ar_s[tid];
  if (bid == 0) {
    if (wv == 0) {
      pb_lds[lane * 4 + 0] = (unsigned)(pb0 & 0xffffffffu);
      pb_lds[lane * 4 + 1] = (unsigned)(pb0 >> 32);
      pb_lds[lane * 4 + 2] = (unsigned)(pb1 & 0xffffffffu);
      pb_lds[lane * 4 + 3] = (unsigned)(pb1 >> 32);
    }
    __syncthreads();
    for (int i = tid; i < N_ENT; i += 256)
      p.out[NN + i] = (float)((pb_lds[i >> 5] >> (i & 31)) & 1u);
  }
}

extern "C" void kernel_launch(void* const* d_in, const int* in_sizes, int n_in,
                              void* d_out, int out_size, void* d_ws, size_t ws_size,
                              hipStream_t stream) {
  (void)in_sizes; (void)n_in; (void)out_size; (void)ws_size;
  Params p;
  p.um    = (const float*)d_in[0];
  p.emask = (const float*)d_in[1];
  p.enc   = (const float*)d_in[2];
  p.arin  = (const float*)d_in[3];
  p.W_fe  = (const float*)d_in[4];
  p.b_fe  = (const float*)d_in[5];
  p.W_k   = (const float*)d_in[6];
  p.b_k   = (const float*)d_in[7];
  p.W_a0  = (const float*)d_in[8];
  p.b_a0  = (const float*)d_in[9];
  p.W_a1  = (const float*)d_in[10];
  p.b_a1  = (const float*)d_in[11];
  p.W_f   = (const float*)d_in[12];
  p.b_f   = (const float*)d_in[13];
  p.W_i0  = (const float*)d_in[14];
  p.b_i0  = (const float*)d_in[15];
  p.W_i1  = (const float*)d_in[16];
  p.b_i1  = (const float*)d_in[17];
  p.W_o   = (const float*)d_in[18];
  p.b_o   = (const float*)d_in[19];
  p.ln_g  = (const float*)d_in[20];
  p.ln_b  = (const float*)d_in[21];
  p.W_a3  = (const float*)d_in[22];
  p.b_a3  = (const float*)d_in[23];
  p.ct    = (const int*)d_in[24];
  p.out   = (float*)d_out;
  p.wsf   = (float*)d_ws;
  p.wsi   = (int*)d_ws;

  hipLaunchKernelGGL(k_init, dim3(NBLK), dim3(256), 0, stream, p);
  hipLaunchKernelGGL(k_scan, dim3(NBLK), dim3(256), 0, stream, p);
}